// Round 2
// baseline (151.013 us; speedup 1.0000x reference)
//
#include <hip/hip_runtime.h>

// cvmm: out[m] = x[m] @ w[sel[m]]
// x: [M,64] f32, sel: [M] i32, w: [8,64,64] f32, out: [M,64] f32
//
// R2: latency-bound fix. Masked-expert bf16 MFMA (16x16x32) as R1, plus:
//  - two accumulator chains (8 deep each) instead of one 16-deep chain
//  - software pipeline: prefetch next m-tile's x/sel during current compute
//  - MT=4 (fully unrolled), 4096 blocks, launch_bounds(256,3)
//  - nontemporal stores for out (write-once)

typedef __bf16 bf16x8 __attribute__((ext_vector_type(8)));
typedef float floatx4 __attribute__((ext_vector_type(4)));

#define MT 4  // m-tiles (16 rows each) per block

__global__ __launch_bounds__(256, 3) void cvmm_kernel(
    const float* __restrict__ x,
    const int* __restrict__ sel,
    const float* __restrict__ w,
    float* __restrict__ out,
    int M)
{
    const int lane = threadIdx.x & 63;
    const int wave = threadIdx.x >> 6;   // 0..3 -> n-tile
    const int n0   = wave << 4;          // n offset (16 cols per wave)
    const int quad = lane >> 4;          // 0..3
    const int l16  = lane & 15;

    // ---- Preload B fragments: B[k = quad*8+j][n = l16] per (expert, k-tile).
    // w[e][k][n] at ((e*64 + k)*64 + n); j-step moves k by 1 -> stride 64 floats.
    bf16x8 bfrag[8][2];
#pragma unroll
    for (int e = 0; e < 8; ++e) {
#pragma unroll
        for (int t = 0; t < 2; ++t) {
            const float* wp = w + ((e * 64 + t * 32 + quad * 8) * 64) + (n0 + l16);
#pragma unroll
            for (int j = 0; j < 8; ++j) {
                bfrag[e][t][j] = (__bf16)wp[j * 64];
            }
        }
    }

    bf16x8 zf;
#pragma unroll
    for (int j = 0; j < 8; ++j) zf[j] = (__bf16)0.0f;

    const int mt0 = blockIdx.x * MT;

    // ---- Pipeline prologue: load m-tile 0
    floatx4 pa0, pa1, pa2, pa3;
    int ps;
    {
        const int m0 = mt0 << 4;
        const float* xp = x + (size_t)(m0 + l16) * 64 + quad * 8;
        pa0 = *(const floatx4*)(xp);
        pa1 = *(const floatx4*)(xp + 4);
        pa2 = *(const floatx4*)(xp + 32);
        pa3 = *(const floatx4*)(xp + 36);
        ps  = sel[m0 + l16];
    }

#pragma unroll
    for (int i = 0; i < MT; ++i) {
        const floatx4 a0 = pa0, a1 = pa1, a2 = pa2, a3 = pa3;
        const int s = ps;

        // ---- Prefetch next m-tile while we compute this one
        if (i + 1 < MT) {
            const int m0n = (mt0 + i + 1) << 4;
            const float* xp = x + (size_t)(m0n + l16) * 64 + quad * 8;
            pa0 = *(const floatx4*)(xp);
            pa1 = *(const floatx4*)(xp + 4);
            pa2 = *(const floatx4*)(xp + 32);
            pa3 = *(const floatx4*)(xp + 36);
            ps  = sel[m0n + l16];
        }

        // ---- A fragments: A[m = l16][k = t*32 + quad*8 + j]
        bf16x8 af0, af1;
#pragma unroll
        for (int j = 0; j < 4; ++j) {
            af0[j]     = (__bf16)a0[j];
            af0[j + 4] = (__bf16)a1[j];
            af1[j]     = (__bf16)a2[j];
            af1[j + 4] = (__bf16)a3[j];
        }

        // ---- Two independent accumulator chains (depth 8 each)
        floatx4 c0 = {0.0f, 0.0f, 0.0f, 0.0f};
        floatx4 c1 = {0.0f, 0.0f, 0.0f, 0.0f};
#pragma unroll
        for (int e = 0; e < 8; ++e) {
            const bool ok = (s == e);
            bf16x8 a0m = ok ? af0 : zf;
            bf16x8 a1m = ok ? af1 : zf;
            c0 = __builtin_amdgcn_mfma_f32_16x16x32_bf16(a0m, bfrag[e][0], c0, 0, 0, 0);
            c1 = __builtin_amdgcn_mfma_f32_16x16x32_bf16(a1m, bfrag[e][1], c1, 0, 0, 0);
        }

        // ---- Store: D[row = quad*4 + r][col = l16], out is write-once -> nontemporal
        const int m0 = (mt0 + i) << 4;
        float* op = out + (size_t)(m0 + quad * 4) * 64 + n0 + l16;
#pragma unroll
        for (int r = 0; r < 4; ++r) {
            __builtin_nontemporal_store(c0[r] + c1[r], op + (size_t)r * 64);
        }
    }
}

extern "C" void kernel_launch(void* const* d_in, const int* in_sizes, int n_in,
                              void* d_out, int out_size, void* d_ws, size_t ws_size,
                              hipStream_t stream) {
    const float* x   = (const float*)d_in[0];
    const int*   sel = (const int*)d_in[1];
    const float* w   = (const float*)d_in[2];
    float*       out = (float*)d_out;

    const int M = in_sizes[0] / 64;                 // 262144
    const int mtiles = M / 16;                      // 16384
    const int blocks = (mtiles + MT - 1) / MT;      // 4096

    cvmm_kernel<<<blocks, 256, 0, stream>>>(x, sel, w, out, M);
}

// Round 3
// 145.748 us; speedup vs baseline: 1.0361x; 1.0361x over previous
//
#include <hip/hip_runtime.h>

// cvmm: out[m] = x[m] @ w[sel[m]]
// x: [M,64] f32, sel: [M] i32, w: [8,64,64] f32, out: [M,64] f32
//
// R3: R1/R2 were latency-bound because the compiler SANK the 16 B-fragment
// preload loads into the m-loop (VGPR_Count 52/64 < the 64 regs the frags
// need), re-issuing ~128 L2 loads per m-tile. Fix: pin the fragments with an
// opaque asm register barrier so they stay resident. Also: revert nontemporal
// stores (they blew WRITE_SIZE 66->86 MB), MT=8 / 2048 blocks, keep the
// depth-1 x/sel prefetch pipeline and split accumulator chains.

typedef __bf16 bf16x8 __attribute__((ext_vector_type(8)));
typedef float floatx4 __attribute__((ext_vector_type(4)));

#define MT 8  // m-tiles (16 rows each) per block

__global__ __launch_bounds__(256, 4) void cvmm_kernel(
    const float* __restrict__ x,
    const int* __restrict__ sel,
    const float* __restrict__ w,
    float* __restrict__ out,
    int M)
{
    const int lane = threadIdx.x & 63;
    const int wave = threadIdx.x >> 6;   // 0..3 -> n-tile
    const int n0   = wave << 4;          // n offset (16 cols per wave)
    const int quad = lane >> 4;          // 0..3
    const int l16  = lane & 15;

    // ---- Preload B fragments: B[k = quad*8+j][n = l16] per (expert, k-tile).
    // w[e][k][n] at ((e*64 + k)*64 + n); j-step moves k by 1 -> stride 64 floats.
    // Stored as floatx4 so we can pin them with an asm "+v" barrier.
    floatx4 bfp[8][2];
#pragma unroll
    for (int e = 0; e < 8; ++e) {
#pragma unroll
        for (int t = 0; t < 2; ++t) {
            const float* wp = w + ((e * 64 + t * 32 + quad * 8) * 64) + (n0 + l16);
            bf16x8 f;
#pragma unroll
            for (int j = 0; j < 8; ++j) {
                f[j] = (__bf16)wp[j * 64];
            }
            bfp[e][t] = __builtin_bit_cast(floatx4, f);
        }
    }
    // ---- Pin: make the fragment values opaque so the compiler cannot
    // rematerialize the loads inside the m-loop.
#pragma unroll
    for (int e = 0; e < 8; ++e) {
#pragma unroll
        for (int t = 0; t < 2; ++t) {
            asm volatile("" : "+v"(bfp[e][t]));
        }
    }

    bf16x8 zf;
#pragma unroll
    for (int j = 0; j < 8; ++j) zf[j] = (__bf16)0.0f;

    const int mt0 = blockIdx.x * MT;

    // ---- Pipeline prologue: load m-tile 0's x rows + sel
    floatx4 pa0, pa1, pa2, pa3;
    int ps;
    {
        const int m0 = mt0 << 4;
        const float* xp = x + (size_t)(m0 + l16) * 64 + quad * 8;
        pa0 = *(const floatx4*)(xp);
        pa1 = *(const floatx4*)(xp + 4);
        pa2 = *(const floatx4*)(xp + 32);
        pa3 = *(const floatx4*)(xp + 36);
        ps  = sel[m0 + l16];
    }

#pragma unroll
    for (int i = 0; i < MT; ++i) {
        const floatx4 a0 = pa0, a1 = pa1, a2 = pa2, a3 = pa3;
        const int s = ps;

        // ---- Prefetch next m-tile while computing this one
        if (i + 1 < MT) {
            const int m0n = (mt0 + i + 1) << 4;
            const float* xp = x + (size_t)(m0n + l16) * 64 + quad * 8;
            pa0 = *(const floatx4*)(xp);
            pa1 = *(const floatx4*)(xp + 4);
            pa2 = *(const floatx4*)(xp + 32);
            pa3 = *(const floatx4*)(xp + 36);
            ps  = sel[m0n + l16];
        }

        // ---- A fragments: A[m = l16][k = t*32 + quad*8 + j]
        bf16x8 af0, af1;
#pragma unroll
        for (int j = 0; j < 4; ++j) {
            af0[j]     = (__bf16)a0[j];
            af0[j + 4] = (__bf16)a1[j];
            af1[j]     = (__bf16)a2[j];
            af1[j + 4] = (__bf16)a3[j];
        }

        // ---- Two independent accumulator chains (depth 8 each)
        floatx4 c0 = {0.0f, 0.0f, 0.0f, 0.0f};
        floatx4 c1 = {0.0f, 0.0f, 0.0f, 0.0f};
#pragma unroll
        for (int e = 0; e < 8; ++e) {
            const bool ok = (s == e);
            bf16x8 a0m = ok ? af0 : zf;
            bf16x8 a1m = ok ? af1 : zf;
            c0 = __builtin_amdgcn_mfma_f32_16x16x32_bf16(
                     a0m, __builtin_bit_cast(bf16x8, bfp[e][0]), c0, 0, 0, 0);
            c1 = __builtin_amdgcn_mfma_f32_16x16x32_bf16(
                     a1m, __builtin_bit_cast(bf16x8, bfp[e][1]), c1, 0, 0, 0);
        }

        // ---- Store: D[row = quad*4 + r][col = l16]
        const int m0 = (mt0 + i) << 4;
        float* op = out + (size_t)(m0 + quad * 4) * 64 + n0 + l16;
#pragma unroll
        for (int r = 0; r < 4; ++r) {
            op[(size_t)r * 64] = c0[r] + c1[r];
        }
    }
}

extern "C" void kernel_launch(void* const* d_in, const int* in_sizes, int n_in,
                              void* d_out, int out_size, void* d_ws, size_t ws_size,
                              hipStream_t stream) {
    const float* x   = (const float*)d_in[0];
    const int*   sel = (const int*)d_in[1];
    const float* w   = (const float*)d_in[2];
    float*       out = (float*)d_out;

    const int M = in_sizes[0] / 64;                 // 262144
    const int mtiles = M / 16;                      // 16384
    const int blocks = (mtiles + MT - 1) / MT;      // 2048

    cvmm_kernel<<<blocks, 256, 0, stream>>>(x, sel, w, out, M);
}